// Round 13
// baseline (367.463 us; speedup 1.0000x reference)
//
#include <hip/hip_runtime.h>
#include <math.h>

#define HW 65536

typedef __attribute__((ext_vector_type(8))) short short8;
typedef __attribute__((ext_vector_type(4))) float f32x4;

__device__ __forceinline__ unsigned bf16rne(float f) {
  union { float f; unsigned u; } a; a.f = f;
  return (a.u + 0x7fffu + ((a.u >> 16) & 1u)) >> 16;
}
__device__ __forceinline__ float bf16tof(unsigned h) {
  union { unsigned u; float f; } a; a.u = h << 16;
  return a.f;
}
// fast gelu: Abramowitz-Stegun 7.1.26 erf, |abs err| <= 1.5e-7, branch-free
__device__ __forceinline__ float gelu(float v) {
  float ax = fabsf(v) * 0.70710678118654752f;
  float t = 1.0f / fmaf(0.3275911f, ax, 1.0f);
  float p = t * (0.254829592f +
           t * (-0.284496736f +
           t * (1.421413741f +
           t * (-1.453152027f +
           t * 1.061405429f))));
  float e = __expf(-ax * ax);
  float er = copysignf(fmaf(-p, e, 1.0f), v);
  return 0.5f * v * (1.0f + er);
}

// ---------- tables + weight pre-split (merged) ----------
__global__ __launch_bounds__(256) void k_tables(float* __restrict__ cosT, float* __restrict__ sinT,
                                                ushort* __restrict__ eah, ushort* __restrict__ eal,
                                                ushort* __restrict__ e2h, ushort* __restrict__ e2l,
                                                const float* __restrict__ ww, const float* __restrict__ w1,
                                                ushort* __restrict__ wh, ushort* __restrict__ wl,
                                                ushort* __restrict__ w1h, ushort* __restrict__ w1l) {
  int idx = blockIdx.x * 256 + threadIdx.x;   // 144*256 = 36864
  const float w = 0.0245436926061702596f;     // 2*pi/256
  if (idx < 4096) {
    int k = idx >> 8, xx = idx & 255;
    int t = (k * xx) & 255;
    float ang = (float)t * w;
    cosT[idx] = cosf(ang);
    sinT[idx] = sinf(ang);
  } else if (idx < 12288) {
    int e = idx - 4096;
    int j = e >> 8, xx = e & 255;
    int k = j >> 1;
    int t = (k * xx) & 255;
    float ang = (float)t * w;
    float val = (j & 1) ? -sinf(ang) : cosf(ang);
    unsigned hi = bf16rne(val);
    unsigned lo = bf16rne(val - bf16tof(hi));
    eah[j * 256 + xx] = (ushort)hi;
    eal[j * 256 + xx] = (ushort)lo;
    e2h[xx * 32 + j] = (ushort)hi;
    e2l[xx * 32 + j] = (ushort)lo;
  } else if (idx < 28672) {
    int j = idx - 12288;
    float v = ww[j];
    unsigned hi = bf16rne(v);
    wh[j] = (ushort)hi;
    wl[j] = (ushort)bf16rne(v - bf16tof(hi));
  } else {
    int j = idx - 28672;                      // 8192
    float v = w1[j];
    unsigned hi = bf16rne(v);
    w1h[j] = (ushort)hi;
    w1l[j] = (ushort)bf16rne(v - bf16tof(hi));
  }
}

// ---------- fc0: h plane (bf16) + fused full-row x-DFT ----------
// A2 layout: A2[((b*64+c)*256+y)*128 + xq*32 + s], s = lg*8 + mtile*4 + r.
__global__ __launch_bounds__(256) void k_fc0(const float* __restrict__ x, const float* __restrict__ w,
                                             const float* __restrict__ b,
                                             const ushort* __restrict__ eah, const ushort* __restrict__ eal,
                                             ushort* __restrict__ hh, float* __restrict__ A2) {
  int bid = blockIdx.x;                 // 1024 = B*H
  int bb = bid >> 8, y = bid & 255;
  int tid = threadIdx.x;
  __shared__ float ws[192];
  __shared__ float bs[64];
  __shared__ __align__(16) ushort XsH[256 * 66];
  if (tid < 192) ws[tid] = w[tid];
  if (tid < 64) bs[tid] = b[tid];
  __syncthreads();
  const float* xrow = x + ((size_t)(bb * 3) * 256 + y) * 256;
#pragma unroll
  for (int rep = 0; rep < 8; ++rep) {
    int flat = rep * 256 + tid;       // (pixel p, 8-c group q)
    int p = flat >> 3, q = flat & 7;
    float v0 = xrow[p], v1 = xrow[p + HW], v2 = xrow[p + 2 * HW];
    short8 H;
#pragma unroll
    for (int i = 0; i < 8; ++i) {
      int o = q * 8 + i;
      float v = bs[o] + ws[o * 3] * v0 + ws[o * 3 + 1] * v1 + ws[o * 3 + 2] * v2;
      H[i] = (short)bf16rne(v);
    }
    size_t nb = ((size_t)bid * 256 + p) * 64 + q * 8;
    *(short8*)&hh[nb] = H;
    *(short8*)&XsH[p * 66 + q * 8] = H;
  }
  __syncthreads();
  // fused F1: wave wv handles x-quarter wv
  int lane = tid & 63, wv = tid >> 6;
  int lm = lane & 15, lg = lane >> 4;
#pragma unroll
  for (int ntile = 0; ntile < 4; ++ntile) {
    f32x4 dacc[2];
    dacc[0] = (f32x4){0.f, 0.f, 0.f, 0.f};
    dacc[1] = (f32x4){0.f, 0.f, 0.f, 0.f};
#pragma unroll
    for (int kstep = 0; kstep < 2; ++kstep) {
      int x0 = wv * 64 + kstep * 32 + lg * 8;
      short8 bh;
#pragma unroll
      for (int i = 0; i < 8; ++i) {
        bh[i] = (short)XsH[(x0 + i) * 66 + ntile * 16 + lm];
      }
#pragma unroll
      for (int mtile = 0; mtile < 2; ++mtile) {
        short8 ah = *(const short8*)&eah[(mtile * 16 + lm) * 256 + x0];
        short8 al = *(const short8*)&eal[(mtile * 16 + lm) * 256 + x0];
        dacc[mtile] = __builtin_amdgcn_mfma_f32_16x16x32_bf16(ah, bh, dacc[mtile], 0, 0, 0);
        dacc[mtile] = __builtin_amdgcn_mfma_f32_16x16x32_bf16(al, bh, dacc[mtile], 0, 0, 0);
      }
    }
    int c = ntile * 16 + lm;
    size_t row = ((size_t)(bb * 64 + c) * 256 + y) * 128 + wv * 32 + lg * 8;
    *(float4*)&A2[row] = make_float4(dacc[0][0], dacc[0][1], dacc[0][2], dacc[0][3]);
    *(float4*)&A2[row + 4] = make_float4(dacc[1][0], dacc[1][1], dacc[1][2], dacc[1][3]);
  }
}

// ---------- F2: col DFT over y, split into two y-halves; writes X partials ----------
// Xp[plane*512 + yh*256 + ky*16 + kx]
__global__ __launch_bounds__(256) void k_f2(const float* __restrict__ A2, const float* __restrict__ cosT,
                                            const float* __restrict__ sinT, float2* __restrict__ Xp) {
  int bid = blockIdx.x;                 // 512 = plane*2 + yh
  int plane = bid >> 1, yh = bid & 1;
  int tid = threadIdx.x;
  __shared__ float2 As[128 * 16];
  __shared__ float ct[16 * 129];
  __shared__ float stt[16 * 129];
  const float* Ap = A2 + (size_t)plane * 256 * 128;
#pragma unroll
  for (int rep = 0; rep < 8; ++rep) {
    int flat = rep * 256 + tid;       // 2048: y' (128) x j (16)
    int yp = flat >> 4, j = flat & 15;
    int y = yh * 128 + yp;
    int twoj = 2 * j;
    int s = ((twoj >> 2) & 3) * 8 + (twoj >> 4) * 4 + (twoj & 3);   // perm: ks -> stored idx
    float2 v = make_float2(0.f, 0.f);
#pragma unroll
    for (int q = 0; q < 4; ++q) {
      float2 a = *(const float2*)&Ap[y * 128 + q * 32 + s];
      v.x += a.x; v.y += a.y;
    }
    As[yp * 16 + j] = v;
  }
#pragma unroll
  for (int rep = 0; rep < 8; ++rep) {
    int flat = rep * 256 + tid;       // 2048: ky (16) x y' (128)
    int ky = flat >> 7, yp = flat & 127;
    ct[ky * 129 + yp] = cosT[ky * 256 + yh * 128 + yp];
    stt[ky * 129 + yp] = sinT[ky * 256 + yh * 128 + yp];
  }
  __syncthreads();
  int ky = tid >> 4, kx = tid & 15;
  float xr = 0.f, xi = 0.f;
#pragma unroll 4
  for (int yp = 0; yp < 128; ++yp) {
    float2 a = As[yp * 16 + kx];
    float c = ct[ky * 129 + yp], s = stt[ky * 129 + yp];
    xr += c * a.x + s * a.y;
    xi += c * a.y - s * a.x;
  }
  Xp[(size_t)plane * 512 + yh * 256 + tid] = make_float2(xr, xi);
}

// ---------- MIX: sums the two f2 partials during X read ----------
__global__ __launch_bounds__(256) void k_mix(const float2* __restrict__ Xp, const float* __restrict__ wr,
                                             const float* __restrict__ wi, float2* __restrict__ Y) {
  int o = blockIdx.x >> 2;
  int mc = blockIdx.x & 3;
  int tid = threadIdx.x;
  int cg = tid >> 6, m2 = tid & 63;
  int m = mc * 64 + m2;
  float yr[4] = {0.f, 0.f, 0.f, 0.f}, yi[4] = {0.f, 0.f, 0.f, 0.f};
#pragma unroll 4
  for (int cc = 0; cc < 16; ++cc) {
    int c = cg * 16 + cc;
    float r = wr[(c * 64 + o) * 256 + m];
    float im = wi[(c * 64 + o) * 256 + m];
#pragma unroll
    for (int b = 0; b < 4; ++b) {
      size_t pb = (size_t)(b * 64 + c) * 512;
      float2 x0 = Xp[pb + m];
      float2 x1 = Xp[pb + 256 + m];
      float xvx = x0.x + x1.x, xvy = x0.y + x1.y;
      yr[b] += xvx * r - xvy * im;
      yi[b] += xvx * im + xvy * r;
    }
  }
  __shared__ float2 red[1024];
#pragma unroll
  for (int b = 0; b < 4; ++b) red[cg * 256 + b * 64 + m2] = make_float2(yr[b], yi[b]);
  __syncthreads();
  int b = tid >> 6;
  float sx = 0.f, sy = 0.f;
#pragma unroll
  for (int g2 = 0; g2 < 4; ++g2) {
    float2 v = red[g2 * 256 + b * 64 + m2];
    sx += v.x; sy += v.y;
  }
  Y[(b * 64 + o) * 256 + m] = make_float2(sx, sy);
}

// ---------- INV1: writes g split planes [b*64+o][y][32] ----------
__global__ __launch_bounds__(256) void k_inv1(const float2* __restrict__ Y, const float* __restrict__ cosT,
                                              const float* __restrict__ sinT,
                                              ushort* __restrict__ gh, ushort* __restrict__ gl) {
  int plane = blockIdx.x;               // 256 = B*O
  int y = threadIdx.x;
  __shared__ float2 Ys[256];
  Ys[threadIdx.x] = Y[plane * 256 + threadIdx.x];
  __syncthreads();
  float gr[16], gi[16];
#pragma unroll
  for (int k = 0; k < 16; ++k) { gr[k] = 0.f; gi[k] = 0.f; }
  for (int ky = 0; ky < 16; ++ky) {
    float c = cosT[ky * 256 + y], s = sinT[ky * 256 + y];
#pragma unroll
    for (int kx = 0; kx < 16; ++kx) {
      float2 v = Ys[ky * 16 + kx];
      gr[kx] += c * v.x - s * v.y;
      gi[kx] += c * v.y + s * v.x;
    }
  }
  float val[32];
  const float sc = 1.0f / 65536.0f;
#pragma unroll
  for (int kx = 0; kx < 16; ++kx) {
    float m = (kx == 0) ? sc : 2.0f * sc;
    val[2 * kx] = gr[kx] * m;
    val[2 * kx + 1] = gi[kx] * m;
  }
  size_t gb = ((size_t)plane * 256 + y) * 32;
#pragma unroll
  for (int q = 0; q < 8; ++q) {
    ushort4 H, L;
#pragma unroll
    for (int r = 0; r < 4; ++r) {
      float v = val[q * 4 + r];
      unsigned hi = bf16rne(v);
      ((ushort*)&H)[r] = (ushort)hi;
      ((ushort*)&L)[r] = (ushort)bf16rne(v - bf16tof(hi));
    }
    *(ushort4*)&gh[gb + q * 4] = H;
    *(ushort4*)&gl[gb + q * 4] = L;
  }
}

// ---------- K_LAYER: GEMM (w staged in LDS; g/e2 direct) + coalesced epilogue + fused x-DFT ----------
// LDS 18.7 KB -> 8 blocks/CU.
__global__ __launch_bounds__(256) void k_layer(const ushort* __restrict__ hh,
                                               const ushort* __restrict__ gh, const ushort* __restrict__ gl,
                                               const ushort* __restrict__ wh, const ushort* __restrict__ wl,
                                               const float* __restrict__ wb,
                                               const ushort* __restrict__ e2h, const ushort* __restrict__ e2l,
                                               const ushort* __restrict__ eah, const ushort* __restrict__ eal,
                                               ushort* __restrict__ oh,
                                               float* __restrict__ A2, int do_dft) {
  int bid = blockIdx.x;                 // 4096 = b*1024 + y*4 + xq
  int b = bid >> 10, y = (bid >> 2) & 255, xq = bid & 3;
  int tid = threadIdx.x;
  int lane = tid & 63, wave = tid >> 6;
  int lm = lane & 15, lg = lane >> 4;
  int x = xq * 64 + wave * 16 + lm;
  size_t nb = (size_t)(b * 256 + y) * 256 + x;

  __shared__ __align__(16) ushort wsH[64 * 72], wsL[64 * 72];
  __shared__ float wbs[64];

  // stage w: 4096 ushorts/plane, 2 x short8 per thread
#pragma unroll
  for (int rep = 0; rep < 2; ++rep) {
    int flat = rep * 2048 + tid * 8;
    int o = flat >> 6, cc = flat & 63;
    *(short8*)&wsH[o * 72 + cc] = *(const short8*)&wh[flat];
    *(short8*)&wsL[o * 72 + cc] = *(const short8*)&wl[flat];
  }
  if (tid < 64) wbs[tid] = wb[tid];
  __syncthreads();

  // B fragments (h) and e2 direct from global (L1/L2-resident)
  short8 bh0 = *(const short8*)&hh[nb * 64 + lg * 8];
  short8 bh1 = *(const short8*)&hh[nb * 64 + 32 + lg * 8];
  short8 eh = *(const short8*)&e2h[x * 32 + lg * 8];
  short8 el = *(const short8*)&e2l[x * 32 + lg * 8];

  f32x4 acc[4];
#pragma unroll
  for (int mi = 0; mi < 4; ++mi) acc[mi] = (f32x4){0.f, 0.f, 0.f, 0.f};

#pragma unroll
  for (int mi = 0; mi < 4; ++mi) {
    int o = mi * 16 + lm;
    short8 ah0 = *(const short8*)&wsH[o * 72 + lg * 8];
    short8 al0 = *(const short8*)&wsL[o * 72 + lg * 8];
    acc[mi] = __builtin_amdgcn_mfma_f32_16x16x32_bf16(ah0, bh0, acc[mi], 0, 0, 0);
    acc[mi] = __builtin_amdgcn_mfma_f32_16x16x32_bf16(al0, bh0, acc[mi], 0, 0, 0);
    short8 ah1 = *(const short8*)&wsH[o * 72 + 32 + lg * 8];
    short8 al1 = *(const short8*)&wsL[o * 72 + 32 + lg * 8];
    acc[mi] = __builtin_amdgcn_mfma_f32_16x16x32_bf16(ah1, bh1, acc[mi], 0, 0, 0);
    acc[mi] = __builtin_amdgcn_mfma_f32_16x16x32_bf16(al1, bh1, acc[mi], 0, 0, 0);
    size_t ga = ((size_t)(b * 64 + o) * 256 + y) * 32 + lg * 8;
    short8 gah = *(const short8*)&gh[ga];
    short8 gal = *(const short8*)&gl[ga];
    acc[mi] = __builtin_amdgcn_mfma_f32_16x16x32_bf16(gah, eh, acc[mi], 0, 0, 0);
    acc[mi] = __builtin_amdgcn_mfma_f32_16x16x32_bf16(gah, el, acc[mi], 0, 0, 0);
    acc[mi] = __builtin_amdgcn_mfma_f32_16x16x32_bf16(gal, eh, acc[mi], 0, 0, 0);
  }

  // epilogue: bias + GELU -> bf16 -> LDS [x][o] stride 66 (reuse wsH) -> coalesced stores
  __syncthreads();
  int xl = wave * 16 + lm;
#pragma unroll
  for (int mi = 0; mi < 4; ++mi) {
    ushort4 H;
#pragma unroll
    for (int r = 0; r < 4; ++r) {
      int o = mi * 16 + lg * 4 + r;
      float ge = gelu(acc[mi][r] + wbs[o]);
      ((ushort*)&H)[r] = (ushort)bf16rne(ge);
    }
    *(ushort4*)&wsH[xl * 66 + mi * 16 + lg * 4] = H;
  }
  __syncthreads();
  size_t rowbase = (size_t)(b * 256 + y) * 256 + xq * 64;
#pragma unroll
  for (int rep = 0; rep < 2; ++rep) {
    int ch = rep * 256 + tid;         // (pixel p, 16B chunk)
    int p = ch >> 3, off = (ch & 7) * 8;
    short8 vH = *(const short8*)&wsH[p * 66 + off];
    *(short8*)&oh[(rowbase + p) * 64 + off] = vH;
  }

  // fused partial x-DFT of h_next over this quarter: wave = c 16-slice
  if (do_dft) {
    f32x4 dacc[2];
    dacc[0] = (f32x4){0.f, 0.f, 0.f, 0.f};
    dacc[1] = (f32x4){0.f, 0.f, 0.f, 0.f};
#pragma unroll
    for (int kstep = 0; kstep < 2; ++kstep) {
      int xls = kstep * 32 + lg * 8;
      short8 bh;
#pragma unroll
      for (int i = 0; i < 8; ++i) {
        bh[i] = (short)wsH[(xls + i) * 66 + wave * 16 + lm];
      }
      int x0g = xq * 64 + xls;
#pragma unroll
      for (int mtile = 0; mtile < 2; ++mtile) {
        short8 ah = *(const short8*)&eah[(mtile * 16 + lm) * 256 + x0g];
        short8 al = *(const short8*)&eal[(mtile * 16 + lm) * 256 + x0g];
        dacc[mtile] = __builtin_amdgcn_mfma_f32_16x16x32_bf16(ah, bh, dacc[mtile], 0, 0, 0);
        dacc[mtile] = __builtin_amdgcn_mfma_f32_16x16x32_bf16(al, bh, dacc[mtile], 0, 0, 0);
      }
    }
    int c = wave * 16 + lm;
    size_t row = ((size_t)(b * 64 + c) * 256 + y) * 128 + xq * 32 + lg * 8;
    *(float4*)&A2[row] = make_float4(dacc[0][0], dacc[0][1], dacc[0][2], dacc[0][3]);
    *(float4*)&A2[row + 4] = make_float4(dacc[1][0], dacc[1][1], dacc[1][2], dacc[1][3]);
  }
}

// ---------- K_FINAL: LDS-staged fc1 weights. grid 4096 ----------
__global__ __launch_bounds__(256) void k_final(const ushort* __restrict__ hh,
                                               const ushort* __restrict__ w1h, const ushort* __restrict__ w1l,
                                               const float* __restrict__ b1, const float* __restrict__ w2,
                                               const float* __restrict__ b2, float* __restrict__ out) {
  int bid = blockIdx.x;                 // 4096 = b*1024 + y*4 + xq
  int b = bid >> 10, y = (bid >> 2) & 255, xq = bid & 3;
  int tid = threadIdx.x;
  int lane = tid & 63, wave = tid >> 6;
  int lm = lane & 15, lg = lane >> 4;
  int x = xq * 64 + wave * 16 + lm;
  size_t nb = (size_t)(b * 256 + y) * 256 + x;

  __shared__ __align__(16) ushort w1sH[128 * 72], w1sL[128 * 72];
  __shared__ float b1s[128], w2s[128];

#pragma unroll
  for (int rep = 0; rep < 4; ++rep) {
    int flat = rep * 2048 + tid * 8;
    int j = flat >> 6, cc = flat & 63;
    *(short8*)&w1sH[j * 72 + cc] = *(const short8*)&w1h[flat];
    *(short8*)&w1sL[j * 72 + cc] = *(const short8*)&w1l[flat];
  }
  if (tid < 128) { b1s[tid] = b1[tid]; w2s[tid] = w2[tid]; }
  __syncthreads();

  short8 bh0 = *(const short8*)&hh[nb * 64 + lg * 8];
  short8 bh1 = *(const short8*)&hh[nb * 64 + 32 + lg * 8];

  f32x4 acc[8];
#pragma unroll
  for (int mi = 0; mi < 8; ++mi) acc[mi] = (f32x4){0.f, 0.f, 0.f, 0.f};

#pragma unroll
  for (int mi = 0; mi < 8; ++mi) {
    int j = mi * 16 + lm;
    short8 ah0 = *(const short8*)&w1sH[j * 72 + lg * 8];
    short8 al0 = *(const short8*)&w1sL[j * 72 + lg * 8];
    acc[mi] = __builtin_amdgcn_mfma_f32_16x16x32_bf16(ah0, bh0, acc[mi], 0, 0, 0);
    acc[mi] = __builtin_amdgcn_mfma_f32_16x16x32_bf16(al0, bh0, acc[mi], 0, 0, 0);
    short8 ah1 = *(const short8*)&w1sH[j * 72 + 32 + lg * 8];
    short8 al1 = *(const short8*)&w1sL[j * 72 + 32 + lg * 8];
    acc[mi] = __builtin_amdgcn_mfma_f32_16x16x32_bf16(ah1, bh1, acc[mi], 0, 0, 0);
    acc[mi] = __builtin_amdgcn_mfma_f32_16x16x32_bf16(al1, bh1, acc[mi], 0, 0, 0);
  }

  float p = 0.f;
#pragma unroll
  for (int mi = 0; mi < 8; ++mi)
#pragma unroll
    for (int r = 0; r < 4; ++r) {
      int j = mi * 16 + lg * 4 + r;
      p += w2s[j] * gelu(acc[mi][r] + b1s[j]);
    }
  p += __shfl_xor(p, 16);
  p += __shfl_xor(p, 32);
  if (lg == 0) {
    out[(b * 256 + y) * 256 + x] = p + b2[0];
  }
}

extern "C" void kernel_launch(void* const* d_in, const int* in_sizes, int n_in,
                              void* d_out, int out_size, void* d_ws, size_t ws_size,
                              hipStream_t stream) {
  const float* x       = (const float*)d_in[0];
  const float* fc0_w   = (const float*)d_in[1];
  const float* fc0_b   = (const float*)d_in[2];
  const float* spec_wr = (const float*)d_in[3];
  const float* spec_wi = (const float*)d_in[4];
  const float* w_w     = (const float*)d_in[5];
  const float* w_b     = (const float*)d_in[6];
  const float* fc1_w   = (const float*)d_in[7];
  const float* fc1_b   = (const float*)d_in[8];
  const float* fc2_w   = (const float*)d_in[9];
  const float* fc2_b   = (const float*)d_in[10];
  float* out = (float*)d_out;

  char* ws = (char*)d_ws;
  ushort* h0h  = (ushort*)ws;                              // 33554432 B
  ushort* h1h  = (ushort*)(ws + 33554432);                 // 33554432 B
  float*  A2   = (float*)(ws + 67108864);                  // 33554432 B
  ushort* gh   = (ushort*)(ws + 100663296);                // 4194304 B
  ushort* gl   = (ushort*)(ws + 104857600);                // 4194304 B
  float2* Xp   = (float2*)(ws + 109051904);                // 1048576 B
  float2* Y    = (float2*)(ws + 110100480);                // 524288 B
  float*  cosT = (float*)(ws + 110624768);                 // 16384 B
  float*  sinT = (float*)(ws + 110641152);                 // 16384 B
  ushort* eah  = (ushort*)(ws + 110657536);                // 16384 B
  ushort* eal  = (ushort*)(ws + 110673920);                // 16384 B
  ushort* e2h  = (ushort*)(ws + 110690304);                // 16384 B
  ushort* e2l  = (ushort*)(ws + 110706688);                // 16384 B
  ushort* wWh  = (ushort*)(ws + 110723072);                // 32768 B
  ushort* wWl  = (ushort*)(ws + 110755840);                // 32768 B
  ushort* w1h  = (ushort*)(ws + 110788608);                // 16384 B
  ushort* w1l  = (ushort*)(ws + 110804992);                // 16384 B

  k_tables<<<144, 256, 0, stream>>>(cosT, sinT, eah, eal, e2h, e2l,
                                    w_w, fc1_w, wWh, wWl, w1h, w1l);
  k_fc0<<<1024, 256, 0, stream>>>(x, fc0_w, fc0_b, eah, eal, h0h, A2);
  ushort* hch = h0h;
  ushort* hnh = h1h;
  for (int l = 0; l < 4; ++l) {
    k_f2<<<512, 256, 0, stream>>>(A2, cosT, sinT, Xp);
    k_mix<<<256, 256, 0, stream>>>(Xp, spec_wr + (size_t)l * 1048576, spec_wi + (size_t)l * 1048576, Y);
    k_inv1<<<256, 256, 0, stream>>>(Y, cosT, sinT, gh, gl);
    k_layer<<<4096, 256, 0, stream>>>(hch, gh, gl, wWh + l * 4096, wWl + l * 4096,
                                      w_b + l * 64, e2h, e2l, eah, eal, hnh, A2, (l < 3) ? 1 : 0);
    ushort* t = hch; hch = hnh; hnh = t;
  }
  k_final<<<4096, 256, 0, stream>>>(hch, w1h, w1l, fc1_b, fc2_w, fc2_b, out);
}

// Round 14
// 342.320 us; speedup vs baseline: 1.0734x; 1.0734x over previous
//
#include <hip/hip_runtime.h>
#include <math.h>

#define HW 65536

typedef __attribute__((ext_vector_type(8))) short short8;
typedef __attribute__((ext_vector_type(4))) float f32x4;

__device__ __forceinline__ unsigned bf16rne(float f) {
  union { float f; unsigned u; } a; a.f = f;
  return (a.u + 0x7fffu + ((a.u >> 16) & 1u)) >> 16;
}
__device__ __forceinline__ float bf16tof(unsigned h) {
  union { unsigned u; float f; } a; a.u = h << 16;
  return a.f;
}
// fast gelu: Abramowitz-Stegun 7.1.26 erf, |abs err| <= 1.5e-7, branch-free
__device__ __forceinline__ float gelu(float v) {
  float ax = fabsf(v) * 0.70710678118654752f;
  float t = 1.0f / fmaf(0.3275911f, ax, 1.0f);
  float p = t * (0.254829592f +
           t * (-0.284496736f +
           t * (1.421413741f +
           t * (-1.453152027f +
           t * 1.061405429f))));
  float e = __expf(-ax * ax);
  float er = copysignf(fmaf(-p, e, 1.0f), v);
  return 0.5f * v * (1.0f + er);
}

// ---------- tables + weight pre-split (merged) ----------
__global__ __launch_bounds__(256) void k_tables(float* __restrict__ cosT, float* __restrict__ sinT,
                                                ushort* __restrict__ eah, ushort* __restrict__ eal,
                                                ushort* __restrict__ e2h, ushort* __restrict__ e2l,
                                                const float* __restrict__ ww, const float* __restrict__ w1,
                                                ushort* __restrict__ wh, ushort* __restrict__ wl,
                                                ushort* __restrict__ w1h, ushort* __restrict__ w1l) {
  int idx = blockIdx.x * 256 + threadIdx.x;   // 144*256 = 36864
  const float w = 0.0245436926061702596f;     // 2*pi/256
  if (idx < 4096) {
    int k = idx >> 8, xx = idx & 255;
    int t = (k * xx) & 255;
    float ang = (float)t * w;
    cosT[idx] = cosf(ang);
    sinT[idx] = sinf(ang);
  } else if (idx < 12288) {
    int e = idx - 4096;
    int j = e >> 8, xx = e & 255;
    int k = j >> 1;
    int t = (k * xx) & 255;
    float ang = (float)t * w;
    float val = (j & 1) ? -sinf(ang) : cosf(ang);
    unsigned hi = bf16rne(val);
    unsigned lo = bf16rne(val - bf16tof(hi));
    eah[j * 256 + xx] = (ushort)hi;
    eal[j * 256 + xx] = (ushort)lo;
    e2h[xx * 32 + j] = (ushort)hi;
    e2l[xx * 32 + j] = (ushort)lo;
  } else if (idx < 28672) {
    int j = idx - 12288;
    float v = ww[j];
    unsigned hi = bf16rne(v);
    wh[j] = (ushort)hi;
    wl[j] = (ushort)bf16rne(v - bf16tof(hi));
  } else {
    int j = idx - 28672;                      // 8192
    float v = w1[j];
    unsigned hi = bf16rne(v);
    w1h[j] = (ushort)hi;
    w1l[j] = (ushort)bf16rne(v - bf16tof(hi));
  }
}

// ---------- fc0: h plane (bf16) + fused full-row x-DFT (canonical A) ----------
// A canonical: A[((b*64+c)*256+y)*32 + j], j=2k:Re(k), 2k+1:Im(k).
__global__ __launch_bounds__(256) void k_fc0(const float* __restrict__ x, const float* __restrict__ w,
                                             const float* __restrict__ b,
                                             const ushort* __restrict__ eah, const ushort* __restrict__ eal,
                                             ushort* __restrict__ hh, float* __restrict__ A) {
  int bid = blockIdx.x;                 // 1024 = B*H
  int bb = bid >> 8, y = bid & 255;
  int tid = threadIdx.x;
  __shared__ float ws[192];
  __shared__ float bs[64];
  __shared__ __align__(16) ushort XsH[256 * 66];
  if (tid < 192) ws[tid] = w[tid];
  if (tid < 64) bs[tid] = b[tid];
  __syncthreads();
  const float* xrow = x + ((size_t)(bb * 3) * 256 + y) * 256;
#pragma unroll
  for (int rep = 0; rep < 8; ++rep) {
    int flat = rep * 256 + tid;       // (pixel p, 8-c group q)
    int p = flat >> 3, q = flat & 7;
    float v0 = xrow[p], v1 = xrow[p + HW], v2 = xrow[p + 2 * HW];
    short8 H;
#pragma unroll
    for (int i = 0; i < 8; ++i) {
      int o = q * 8 + i;
      float v = bs[o] + ws[o * 3] * v0 + ws[o * 3 + 1] * v1 + ws[o * 3 + 2] * v2;
      H[i] = (short)bf16rne(v);
    }
    size_t nb = ((size_t)bid * 256 + p) * 64 + q * 8;
    *(short8*)&hh[nb] = H;
    *(short8*)&XsH[p * 66 + q * 8] = H;
  }
  __syncthreads();
  // fused F1: wave = c 16-slice, contract over full 256 x
  int lane = tid & 63, wv = tid >> 6;
  int lm = lane & 15, lg = lane >> 4;
  f32x4 d0 = (f32x4){0.f, 0.f, 0.f, 0.f};
  f32x4 d1 = (f32x4){0.f, 0.f, 0.f, 0.f};
  int c = wv * 16 + lm;
#pragma unroll
  for (int kc = 0; kc < 8; ++kc) {
    int x0 = kc * 32 + lg * 8;
    short8 bh;
#pragma unroll
    for (int i = 0; i < 8; ++i) bh[i] = (short)XsH[(x0 + i) * 66 + c];
    short8 a0h = *(const short8*)&eah[lm * 256 + x0];
    short8 a0l = *(const short8*)&eal[lm * 256 + x0];
    short8 a1h = *(const short8*)&eah[(16 + lm) * 256 + x0];
    short8 a1l = *(const short8*)&eal[(16 + lm) * 256 + x0];
    d0 = __builtin_amdgcn_mfma_f32_16x16x32_bf16(a0h, bh, d0, 0, 0, 0);
    d0 = __builtin_amdgcn_mfma_f32_16x16x32_bf16(a0l, bh, d0, 0, 0, 0);
    d1 = __builtin_amdgcn_mfma_f32_16x16x32_bf16(a1h, bh, d1, 0, 0, 0);
    d1 = __builtin_amdgcn_mfma_f32_16x16x32_bf16(a1l, bh, d1, 0, 0, 0);
  }
  size_t row = ((size_t)(bb * 64 + c) * 256 + y) * 32;
  *(float4*)&A[row + lg * 4] = make_float4(d0[0], d0[1], d0[2], d0[3]);
  *(float4*)&A[row + 16 + lg * 4] = make_float4(d1[0], d1[1], d1[2], d1[3]);
}

// ---------- F2: col DFT over y (y-split halves); reads canonical A; writes X partials ----------
__global__ __launch_bounds__(256) void k_f2(const float* __restrict__ A, const float* __restrict__ cosT,
                                            const float* __restrict__ sinT, float2* __restrict__ Xp) {
  int bid = blockIdx.x;                 // 512 = plane*2 + yh
  int plane = bid >> 1, yh = bid & 1;
  int tid = threadIdx.x;
  __shared__ float2 As[128 * 16];
  __shared__ float ct[16 * 129];
  __shared__ float stt[16 * 129];
  const float2* Ap = (const float2*)A + (size_t)plane * 4096;
#pragma unroll
  for (int rep = 0; rep < 8; ++rep) {
    int flat = rep * 256 + tid;       // 2048: y' (128) x j (16)
    As[flat] = Ap[yh * 2048 + flat];
  }
#pragma unroll
  for (int rep = 0; rep < 8; ++rep) {
    int flat = rep * 256 + tid;       // 2048: ky (16) x y' (128)
    int ky = flat >> 7, yp = flat & 127;
    ct[ky * 129 + yp] = cosT[ky * 256 + yh * 128 + yp];
    stt[ky * 129 + yp] = sinT[ky * 256 + yh * 128 + yp];
  }
  __syncthreads();
  int ky = tid >> 4, kx = tid & 15;
  float xr = 0.f, xi = 0.f;
#pragma unroll 4
  for (int yp = 0; yp < 128; ++yp) {
    float2 a = As[yp * 16 + kx];
    float c = ct[ky * 129 + yp], s = stt[ky * 129 + yp];
    xr += c * a.x + s * a.y;
    xi += c * a.y - s * a.x;
  }
  Xp[(size_t)plane * 512 + yh * 256 + tid] = make_float2(xr, xi);
}

// ---------- MIX: sums the two f2 partials during X read ----------
__global__ __launch_bounds__(256) void k_mix(const float2* __restrict__ Xp, const float* __restrict__ wr,
                                             const float* __restrict__ wi, float2* __restrict__ Y) {
  int o = blockIdx.x >> 2;
  int mc = blockIdx.x & 3;
  int tid = threadIdx.x;
  int cg = tid >> 6, m2 = tid & 63;
  int m = mc * 64 + m2;
  float yr[4] = {0.f, 0.f, 0.f, 0.f}, yi[4] = {0.f, 0.f, 0.f, 0.f};
#pragma unroll 4
  for (int cc = 0; cc < 16; ++cc) {
    int c = cg * 16 + cc;
    float r = wr[(c * 64 + o) * 256 + m];
    float im = wi[(c * 64 + o) * 256 + m];
#pragma unroll
    for (int b = 0; b < 4; ++b) {
      size_t pb = (size_t)(b * 64 + c) * 512;
      float2 x0 = Xp[pb + m];
      float2 x1 = Xp[pb + 256 + m];
      float xvx = x0.x + x1.x, xvy = x0.y + x1.y;
      yr[b] += xvx * r - xvy * im;
      yi[b] += xvx * im + xvy * r;
    }
  }
  __shared__ float2 red[1024];
#pragma unroll
  for (int b = 0; b < 4; ++b) red[cg * 256 + b * 64 + m2] = make_float2(yr[b], yi[b]);
  __syncthreads();
  int b = tid >> 6;
  float sx = 0.f, sy = 0.f;
#pragma unroll
  for (int g2 = 0; g2 < 4; ++g2) {
    float2 v = red[g2 * 256 + b * 64 + m2];
    sx += v.x; sy += v.y;
  }
  Y[(b * 64 + o) * 256 + m] = make_float2(sx, sy);
}

// ---------- INV1: writes g split planes [b*64+o][y][32] ----------
__global__ __launch_bounds__(256) void k_inv1(const float2* __restrict__ Y, const float* __restrict__ cosT,
                                              const float* __restrict__ sinT,
                                              ushort* __restrict__ gh, ushort* __restrict__ gl) {
  int plane = blockIdx.x;               // 256 = B*O
  int y = threadIdx.x;
  __shared__ float2 Ys[256];
  Ys[threadIdx.x] = Y[plane * 256 + threadIdx.x];
  __syncthreads();
  float gr[16], gi[16];
#pragma unroll
  for (int k = 0; k < 16; ++k) { gr[k] = 0.f; gi[k] = 0.f; }
  for (int ky = 0; ky < 16; ++ky) {
    float c = cosT[ky * 256 + y], s = sinT[ky * 256 + y];
#pragma unroll
    for (int kx = 0; kx < 16; ++kx) {
      float2 v = Ys[ky * 16 + kx];
      gr[kx] += c * v.x - s * v.y;
      gi[kx] += c * v.y + s * v.x;
    }
  }
  float val[32];
  const float sc = 1.0f / 65536.0f;
#pragma unroll
  for (int kx = 0; kx < 16; ++kx) {
    float m = (kx == 0) ? sc : 2.0f * sc;
    val[2 * kx] = gr[kx] * m;
    val[2 * kx + 1] = gi[kx] * m;
  }
  size_t gb = ((size_t)plane * 256 + y) * 32;
#pragma unroll
  for (int q = 0; q < 8; ++q) {
    ushort4 H, L;
#pragma unroll
    for (int r = 0; r < 4; ++r) {
      float v = val[q * 4 + r];
      unsigned hi = bf16rne(v);
      ((ushort*)&H)[r] = (ushort)hi;
      ((ushort*)&L)[r] = (ushort)bf16rne(v - bf16tof(hi));
    }
    *(ushort4*)&gh[gb + q * 4] = H;
    *(ushort4*)&gl[gb + q * 4] = L;
  }
}

// ---------- K_LAYER: full-row block (b,y). w/g staged once; 8 h-loads in flight/thread;
// coalesced epilogue; fused full-row x-DFT writing canonical A. ----------
__global__ __launch_bounds__(256) void k_layer(const ushort* __restrict__ hh,
                                               const ushort* __restrict__ gh, const ushort* __restrict__ gl,
                                               const ushort* __restrict__ wh, const ushort* __restrict__ wl,
                                               const float* __restrict__ wb,
                                               const ushort* __restrict__ e2h, const ushort* __restrict__ e2l,
                                               const ushort* __restrict__ eah, const ushort* __restrict__ eal,
                                               ushort* __restrict__ oh,
                                               float* __restrict__ A, int do_dft) {
  int bid = blockIdx.x;                 // 1024 = b*256 + y
  int b = bid >> 8, y = bid & 255;
  int tid = threadIdx.x;
  int lane = tid & 63, wv = tid >> 6;
  int lm = lane & 15, lg = lane >> 4;
  size_t nbase = (size_t)(b * 256 + y) * 256;

  // phase-A: wsH[64*72]@0, wsL@4608, gsH[64*40]@9216, gsL@11776 (ushorts)
  // phase-B (after barrier): Xs[256*66] aliases everything.
  __shared__ __align__(16) ushort smem[16896];
  __shared__ float wbs[64];
  ushort* wsH = smem;
  ushort* wsL = smem + 4608;
  ushort* gsH = smem + 9216;
  ushort* gsL = smem + 11776;
  ushort* Xs  = smem;

  // stage w (once per row)
#pragma unroll
  for (int rep = 0; rep < 2; ++rep) {
    int flat = rep * 2048 + tid * 8;
    int o = flat >> 6, cc = flat & 63;
    *(short8*)&wsH[o * 72 + cc] = *(const short8*)&wh[flat];
    *(short8*)&wsL[o * 72 + cc] = *(const short8*)&wl[flat];
  }
  // stage g (once per row)
  {
    int o = tid >> 2, i = (tid & 3) * 8;
    size_t ga = ((size_t)(b * 64 + o) * 256 + y) * 32 + i;
    *(short8*)&gsH[o * 40 + i] = *(const short8*)&gh[ga];
    *(short8*)&gsL[o * 40 + i] = *(const short8*)&gl[ga];
  }
  if (tid < 64) wbs[tid] = wb[tid];
  __syncthreads();

  // all B fragments upfront: 8 independent 16B h loads + 8 e2 loads
  short8 bh0[4], bh1[4], ehv[4], elv[4];
#pragma unroll
  for (int ni = 0; ni < 4; ++ni) {
    int xx = wv * 64 + ni * 16 + lm;
    size_t hb = (nbase + xx) * 64 + lg * 8;
    bh0[ni] = *(const short8*)&hh[hb];
    bh1[ni] = *(const short8*)&hh[hb + 32];
    ehv[ni] = *(const short8*)&e2h[xx * 32 + lg * 8];
    elv[ni] = *(const short8*)&e2l[xx * 32 + lg * 8];
  }

  f32x4 acc[4][4];
#pragma unroll
  for (int mi = 0; mi < 4; ++mi)
#pragma unroll
    for (int ni = 0; ni < 4; ++ni) acc[mi][ni] = (f32x4){0.f, 0.f, 0.f, 0.f};

#pragma unroll
  for (int mi = 0; mi < 4; ++mi) {
    int o = mi * 16 + lm;
    short8 ah0 = *(const short8*)&wsH[o * 72 + lg * 8];
    short8 al0 = *(const short8*)&wsL[o * 72 + lg * 8];
    short8 ah1 = *(const short8*)&wsH[o * 72 + 32 + lg * 8];
    short8 al1 = *(const short8*)&wsL[o * 72 + 32 + lg * 8];
    short8 gah = *(const short8*)&gsH[o * 40 + lg * 8];
    short8 gal = *(const short8*)&gsL[o * 40 + lg * 8];
#pragma unroll
    for (int ni = 0; ni < 4; ++ni) {
      acc[mi][ni] = __builtin_amdgcn_mfma_f32_16x16x32_bf16(ah0, bh0[ni], acc[mi][ni], 0, 0, 0);
      acc[mi][ni] = __builtin_amdgcn_mfma_f32_16x16x32_bf16(al0, bh0[ni], acc[mi][ni], 0, 0, 0);
      acc[mi][ni] = __builtin_amdgcn_mfma_f32_16x16x32_bf16(ah1, bh1[ni], acc[mi][ni], 0, 0, 0);
      acc[mi][ni] = __builtin_amdgcn_mfma_f32_16x16x32_bf16(al1, bh1[ni], acc[mi][ni], 0, 0, 0);
      acc[mi][ni] = __builtin_amdgcn_mfma_f32_16x16x32_bf16(gah, ehv[ni], acc[mi][ni], 0, 0, 0);
      acc[mi][ni] = __builtin_amdgcn_mfma_f32_16x16x32_bf16(gah, elv[ni], acc[mi][ni], 0, 0, 0);
      acc[mi][ni] = __builtin_amdgcn_mfma_f32_16x16x32_bf16(gal, ehv[ni], acc[mi][ni], 0, 0, 0);
    }
  }

  // epilogue: bias + GELU -> bf16 -> Xs[x][o] stride 66 (aliases staging)
  __syncthreads();
#pragma unroll
  for (int mi = 0; mi < 4; ++mi)
#pragma unroll
    for (int ni = 0; ni < 4; ++ni) {
      int xx = wv * 64 + ni * 16 + lm;
      ushort4 H;
#pragma unroll
      for (int r = 0; r < 4; ++r) {
        int o = mi * 16 + lg * 4 + r;
        float ge = gelu(acc[mi][ni][r] + wbs[o]);
        ((ushort*)&H)[r] = (ushort)bf16rne(ge);
      }
      *(ushort4*)&Xs[xx * 66 + mi * 16 + lg * 4] = H;
    }
  __syncthreads();
  // coalesced 16B stores of the whole row
#pragma unroll
  for (int rep = 0; rep < 8; ++rep) {
    int flat = rep * 256 + tid;       // (pixel p, 16B chunk)
    int p = flat >> 3, off = (flat & 7) * 8;
    short8 vH = *(const short8*)&Xs[p * 66 + off];
    *(short8*)&oh[(nbase + p) * 64 + off] = vH;
  }

  // fused full-row x-DFT of h_next: wave = c 16-slice, canonical A write
  if (do_dft) {
    f32x4 d0 = (f32x4){0.f, 0.f, 0.f, 0.f};
    f32x4 d1 = (f32x4){0.f, 0.f, 0.f, 0.f};
    int c = wv * 16 + lm;
#pragma unroll
    for (int kc = 0; kc < 8; ++kc) {
      int x0 = kc * 32 + lg * 8;
      short8 bh;
#pragma unroll
      for (int i = 0; i < 8; ++i) bh[i] = (short)Xs[(x0 + i) * 66 + c];
      short8 a0h = *(const short8*)&eah[lm * 256 + x0];
      short8 a0l = *(const short8*)&eal[lm * 256 + x0];
      short8 a1h = *(const short8*)&eah[(16 + lm) * 256 + x0];
      short8 a1l = *(const short8*)&eal[(16 + lm) * 256 + x0];
      d0 = __builtin_amdgcn_mfma_f32_16x16x32_bf16(a0h, bh, d0, 0, 0, 0);
      d0 = __builtin_amdgcn_mfma_f32_16x16x32_bf16(a0l, bh, d0, 0, 0, 0);
      d1 = __builtin_amdgcn_mfma_f32_16x16x32_bf16(a1h, bh, d1, 0, 0, 0);
      d1 = __builtin_amdgcn_mfma_f32_16x16x32_bf16(a1l, bh, d1, 0, 0, 0);
    }
    size_t row = ((size_t)(b * 64 + c) * 256 + y) * 32;
    *(float4*)&A[row + lg * 4] = make_float4(d0[0], d0[1], d0[2], d0[3]);
    *(float4*)&A[row + 16 + lg * 4] = make_float4(d1[0], d1[1], d1[2], d1[3]);
  }
}

// ---------- K_FINAL: LDS-staged fc1 weights. grid 4096 ----------
__global__ __launch_bounds__(256) void k_final(const ushort* __restrict__ hh,
                                               const ushort* __restrict__ w1h, const ushort* __restrict__ w1l,
                                               const float* __restrict__ b1, const float* __restrict__ w2,
                                               const float* __restrict__ b2, float* __restrict__ out) {
  int bid = blockIdx.x;                 // 4096 = b*1024 + y*4 + xq
  int b = bid >> 10, y = (bid >> 2) & 255, xq = bid & 3;
  int tid = threadIdx.x;
  int lane = tid & 63, wave = tid >> 6;
  int lm = lane & 15, lg = lane >> 4;
  int x = xq * 64 + wave * 16 + lm;
  size_t nb = (size_t)(b * 256 + y) * 256 + x;

  __shared__ __align__(16) ushort w1sH[128 * 72], w1sL[128 * 72];
  __shared__ float b1s[128], w2s[128];

#pragma unroll
  for (int rep = 0; rep < 4; ++rep) {
    int flat = rep * 2048 + tid * 8;
    int j = flat >> 6, cc = flat & 63;
    *(short8*)&w1sH[j * 72 + cc] = *(const short8*)&w1h[flat];
    *(short8*)&w1sL[j * 72 + cc] = *(const short8*)&w1l[flat];
  }
  if (tid < 128) { b1s[tid] = b1[tid]; w2s[tid] = w2[tid]; }
  __syncthreads();

  short8 bh0 = *(const short8*)&hh[nb * 64 + lg * 8];
  short8 bh1 = *(const short8*)&hh[nb * 64 + 32 + lg * 8];

  f32x4 acc[8];
#pragma unroll
  for (int mi = 0; mi < 8; ++mi) acc[mi] = (f32x4){0.f, 0.f, 0.f, 0.f};

#pragma unroll
  for (int mi = 0; mi < 8; ++mi) {
    int j = mi * 16 + lm;
    short8 ah0 = *(const short8*)&w1sH[j * 72 + lg * 8];
    short8 al0 = *(const short8*)&w1sL[j * 72 + lg * 8];
    acc[mi] = __builtin_amdgcn_mfma_f32_16x16x32_bf16(ah0, bh0, acc[mi], 0, 0, 0);
    acc[mi] = __builtin_amdgcn_mfma_f32_16x16x32_bf16(al0, bh0, acc[mi], 0, 0, 0);
    short8 ah1 = *(const short8*)&w1sH[j * 72 + 32 + lg * 8];
    short8 al1 = *(const short8*)&w1sL[j * 72 + 32 + lg * 8];
    acc[mi] = __builtin_amdgcn_mfma_f32_16x16x32_bf16(ah1, bh1, acc[mi], 0, 0, 0);
    acc[mi] = __builtin_amdgcn_mfma_f32_16x16x32_bf16(al1, bh1, acc[mi], 0, 0, 0);
  }

  float p = 0.f;
#pragma unroll
  for (int mi = 0; mi < 8; ++mi)
#pragma unroll
    for (int r = 0; r < 4; ++r) {
      int j = mi * 16 + lg * 4 + r;
      p += w2s[j] * gelu(acc[mi][r] + b1s[j]);
    }
  p += __shfl_xor(p, 16);
  p += __shfl_xor(p, 32);
  if (lg == 0) {
    out[(b * 256 + y) * 256 + x] = p + b2[0];
  }
}

extern "C" void kernel_launch(void* const* d_in, const int* in_sizes, int n_in,
                              void* d_out, int out_size, void* d_ws, size_t ws_size,
                              hipStream_t stream) {
  const float* x       = (const float*)d_in[0];
  const float* fc0_w   = (const float*)d_in[1];
  const float* fc0_b   = (const float*)d_in[2];
  const float* spec_wr = (const float*)d_in[3];
  const float* spec_wi = (const float*)d_in[4];
  const float* w_w     = (const float*)d_in[5];
  const float* w_b     = (const float*)d_in[6];
  const float* fc1_w   = (const float*)d_in[7];
  const float* fc1_b   = (const float*)d_in[8];
  const float* fc2_w   = (const float*)d_in[9];
  const float* fc2_b   = (const float*)d_in[10];
  float* out = (float*)d_out;

  char* ws = (char*)d_ws;
  ushort* h0h  = (ushort*)ws;                              // 33554432 B
  ushort* h1h  = (ushort*)(ws + 33554432);                 // 33554432 B
  float*  A    = (float*)(ws + 67108864);                  // 8388608 B
  ushort* gh   = (ushort*)(ws + 75497472);                 // 4194304 B
  ushort* gl   = (ushort*)(ws + 79691776);                 // 4194304 B
  float2* Xp   = (float2*)(ws + 83886080);                 // 1048576 B
  float2* Y    = (float2*)(ws + 84934656);                 // 524288 B
  float*  cosT = (float*)(ws + 85458944);                  // 16384 B
  float*  sinT = (float*)(ws + 85475328);                  // 16384 B
  ushort* eah  = (ushort*)(ws + 85491712);                 // 16384 B
  ushort* eal  = (ushort*)(ws + 85508096);                 // 16384 B
  ushort* e2h  = (ushort*)(ws + 85524480);                 // 16384 B
  ushort* e2l  = (ushort*)(ws + 85540864);                 // 16384 B
  ushort* wWh  = (ushort*)(ws + 85557248);                 // 32768 B
  ushort* wWl  = (ushort*)(ws + 85590016);                 // 32768 B
  ushort* w1h  = (ushort*)(ws + 85622784);                 // 16384 B
  ushort* w1l  = (ushort*)(ws + 85639168);                 // 16384 B

  k_tables<<<144, 256, 0, stream>>>(cosT, sinT, eah, eal, e2h, e2l,
                                    w_w, fc1_w, wWh, wWl, w1h, w1l);
  k_fc0<<<1024, 256, 0, stream>>>(x, fc0_w, fc0_b, eah, eal, h0h, A);
  ushort* hch = h0h;
  ushort* hnh = h1h;
  for (int l = 0; l < 4; ++l) {
    k_f2<<<512, 256, 0, stream>>>(A, cosT, sinT, Xp);
    k_mix<<<256, 256, 0, stream>>>(Xp, spec_wr + (size_t)l * 1048576, spec_wi + (size_t)l * 1048576, Y);
    k_inv1<<<256, 256, 0, stream>>>(Y, cosT, sinT, gh, gl);
    k_layer<<<1024, 256, 0, stream>>>(hch, gh, gl, wWh + l * 4096, wWl + l * 4096,
                                      w_b + l * 64, e2h, e2l, eah, eal, hnh, A, (l < 3) ? 1 : 0);
    ushort* t = hch; hch = hnh; hnh = t;
  }
  k_final<<<4096, 256, 0, stream>>>(hch, w1h, w1l, fc1_b, fc2_w, fc2_b, out);
}